// Round 1
// baseline (278.746 us; speedup 1.0000x reference)
//
#include <hip/hip_runtime.h>
#include <hip/hip_bf16.h>
#include <math.h>

#define EPSF 1e-5f

constexpr int D  = 128;   // feature dim
constexpr int K  = 128;   // centroids
constexpr int TN = 32;    // x-rows per block
constexpr int SLAB = 32;  // d-slab staged per iteration
constexpr int NTHREADS = 256;

// ---------------- kernel 1: centroid exp-map (exp_map_zero) ----------------
// grid = K blocks, 64 threads (one wave). Each block handles one centroid row.
__global__ __launch_bounds__(64) void prep_kernel(const float* __restrict__ w,
                                                  float* __restrict__ cr,
                                                  float* __restrict__ c2) {
    int k = blockIdx.x;
    int t = threadIdx.x;
    float a = w[k * D + t];
    float b = w[k * D + t + 64];
    float ss = a * a + b * b;
#pragma unroll
    for (int off = 1; off < 64; off <<= 1)
        ss += __shfl_xor(ss, off, 64);
    float nrm   = sqrtf(ss);
    float nclip = fmaxf(nrm, EPSF);          // clip(norm, EPS, None)
    float targ  = fminf(nclip, 15.0f);       // clip(norm, None, 15)
    float th    = tanhf(targ);
    float s     = th / nclip;
    cr[k * D + t]      = a * s;
    cr[k * D + t + 64] = b * s;
    if (t == 0) {
        float cn = s * nrm;                  // ||centroid_repr||
        c2[k] = cn * cn;
    }
}

// ---------------- kernel 2: main pairwise distance ----------------
// grid = N/TN blocks, 256 threads. Per-thread 4x4 tile:
//   kt = t&31 covers k = kt*4..kt*4+3 (float4-contiguous outputs)
//   nt = t>>5 covers rows nt*4..nt*4+3
// Centroids staged TRANSPOSED (sC[d][k], k contiguous) in 32-d slabs:
// c-reads are lane-consecutive float4 -> conflict-free; x-reads are 2-way
// broadcast (free on gfx950, m136).
__global__ __launch_bounds__(NTHREADS) void main_kernel(
        const float* __restrict__ x, const float* __restrict__ mask,
        const float* __restrict__ cr, const float* __restrict__ c2g,
        float* __restrict__ out_node, float* __restrict__ partial,
        float* __restrict__ maskpart, int N) {
    __shared__ float sX[TN * D];      // 16 KB, row-major
    __shared__ float sC[SLAB * K];    // 16 KB, d-major (transposed)
    __shared__ float sX2[TN];
    __shared__ float sMask[TN];
    __shared__ float sRed[8 * K];     // 4 KB column partials

    const int t     = threadIdx.x;
    const int nbase = blockIdx.x * TN;

    // ---- stage x tile (coalesced float4), compute row sum-sq in-register ----
    float rowssq[4];
#pragma unroll
    for (int i = 0; i < 4; i++) {
        int f4 = t + 256 * i;   // 1024 float4s = 32 rows * 128 floats
        float4 v = ((const float4*)(x + (size_t)nbase * D))[f4];
        ((float4*)sX)[f4] = v;
        rowssq[i] = v.x * v.x + v.y * v.y + v.z * v.z + v.w * v.w;
    }
    // each group of 32 consecutive lanes holds one row's partials
#pragma unroll
    for (int i = 0; i < 4; i++) {
#pragma unroll
        for (int off = 1; off < 32; off <<= 1)
            rowssq[i] += __shfl_xor(rowssq[i], off, 64);
        if ((t & 31) == 0) {
            int row = (t + 256 * i) >> 5;
            sX2[row] = rowssq[i];
        }
    }
    if (t < TN) sMask[t] = mask[nbase + t];

    const int kt = t & 31;
    const int nt = t >> 5;

    float acc[4][4] = {};

    const float4* sXv = (const float4*)sX;

    for (int s = 0; s < D / SLAB; s++) {
        __syncthreads();   // protects sC reuse; first iter publishes sX/sX2/sMask
        // stage c slab transposed: sC[dl*K + k], global d = s*SLAB + dl
        {
            int k  = t & 127;
            int dh = (t >> 7) * 16;   // 0 or 16
#pragma unroll
            for (int q = 0; q < 4; q++) {
                int dl = dh + q * 4;
                float4 v = *(const float4*)(cr + k * D + s * SLAB + dl);
                sC[(dl + 0) * K + k] = v.x;
                sC[(dl + 1) * K + k] = v.y;
                sC[(dl + 2) * K + k] = v.z;
                sC[(dl + 3) * K + k] = v.w;
            }
        }
        __syncthreads();
        // FMA loop: per 4-d chunk: 8 ds_read_b128, 64 FMAs
#pragma unroll
        for (int dc = 0; dc < SLAB; dc += 4) {
            float4 xa[4];
            float4 cb[4];
#pragma unroll
            for (int i = 0; i < 4; i++)
                xa[i] = sXv[((nt * 4 + i) * D + s * SLAB + dc) >> 2];
#pragma unroll
            for (int dd = 0; dd < 4; dd++)
                cb[dd] = *(const float4*)(sC + (dc + dd) * K + kt * 4);
#pragma unroll
            for (int i = 0; i < 4; i++) {
                float xs[4] = {xa[i].x, xa[i].y, xa[i].z, xa[i].w};
#pragma unroll
                for (int dd = 0; dd < 4; dd++) {
                    acc[i][0] = fmaf(xs[dd], cb[dd].x, acc[i][0]);
                    acc[i][1] = fmaf(xs[dd], cb[dd].y, acc[i][1]);
                    acc[i][2] = fmaf(xs[dd], cb[dd].z, acc[i][2]);
                    acc[i][3] = fmaf(xs[dd], cb[dd].w, acc[i][3]);
                }
            }
        }
    }

    // ---- epilogue: arccosh distance, masked write, column partials ----
    float4 c2v  = *(const float4*)(c2g + kt * 4);
    float c2a[4] = {c2v.x, c2v.y, c2v.z, c2v.w};
    float colsum[4] = {0.f, 0.f, 0.f, 0.f};
#pragma unroll
    for (int i = 0; i < 4; i++) {
        int r = nt * 4 + i;
        int n = nbase + r;
        float x2 = sX2[r];
        float px = 1.0f - x2;
        float mv = sMask[r];
        float4 o;
        float* op = &o.x;
#pragma unroll
        for (int j = 0; j < 4; j++) {
            float dot = acc[i][j];
            float sq  = fmaxf(x2 + c2a[j] - 2.0f * dot, 0.0f);
            float den = fmaxf(px * (1.0f - c2a[j]), EPSF);
            float arg = 1.0f + 2.0f * sq / den;
            arg = fmaxf(arg, 1.0f + 1e-7f);
            float dist = logf(arg + sqrtf(fmaf(arg, arg, -1.0f)));
            float val = dist * mv;
            op[j] = val;
            colsum[j] += val;
        }
        if (n < N)
            *(float4*)(out_node + (size_t)n * K + kt * 4) = o;
    }

    *(float4*)(sRed + nt * K + kt * 4) =
        make_float4(colsum[0], colsum[1], colsum[2], colsum[3]);
    __syncthreads();
    if (t < K) {
        float ssum = 0.f;
#pragma unroll
        for (int r8 = 0; r8 < 8; r8++) ssum += sRed[r8 * K + t];
        partial[(size_t)blockIdx.x * K + t] = ssum;
    }
    if (t == 0) {
        float ms = 0.f;
#pragma unroll
        for (int r = 0; r < TN; r++) ms += sMask[r];
        maskpart[blockIdx.x] = ms;
    }
}

// ---------------- kernel 3: column reduce + divide by mask sum ----------------
__global__ __launch_bounds__(256) void reduce_kernel(
        const float* __restrict__ partial, const float* __restrict__ maskpart,
        float* __restrict__ out_graph, int NB) {
    int k = blockIdx.x;
    int t = threadIdx.x;
    float s = 0.f, m = 0.f;
    for (int b = t; b < NB; b += 256) {
        s += partial[(size_t)b * K + k];
        m += maskpart[b];
    }
#pragma unroll
    for (int off = 1; off < 64; off <<= 1) {
        s += __shfl_xor(s, off, 64);
        m += __shfl_xor(m, off, 64);
    }
    __shared__ float rs[4], rm[4];
    int w = t >> 6;
    if ((t & 63) == 0) { rs[w] = s; rm[w] = m; }
    __syncthreads();
    if (t == 0) {
        float st = rs[0] + rs[1] + rs[2] + rs[3];
        float mt = rm[0] + rm[1] + rm[2] + rm[3];
        out_graph[k] = st / mt;
    }
}

extern "C" void kernel_launch(void* const* d_in, const int* in_sizes, int n_in,
                              void* d_out, int out_size, void* d_ws, size_t ws_size,
                              hipStream_t stream) {
    const float* node = (const float*)d_in[0];   // [N, D]
    const float* mask = (const float*)d_in[1];   // [N, 1]
    const float* w    = (const float*)d_in[2];   // [K, D]
    float* out = (float*)d_out;

    int N  = in_sizes[0] / D;          // 200000
    int NB = (N + TN - 1) / TN;        // 6250 (N divisible by TN)

    // workspace layout (floats): cr[K*D] | c2[K] | partial[NB*K] | maskpart[NB]
    float* cr       = (float*)d_ws;
    float* c2       = cr + K * D;
    float* partial  = c2 + K;
    float* maskpart = partial + (size_t)NB * K;

    float* out_graph = out;        // [K]
    float* out_node  = out + K;    // [N, K]

    prep_kernel<<<K, 64, 0, stream>>>(w, cr, c2);
    main_kernel<<<NB, NTHREADS, 0, stream>>>(node, mask, cr, c2, out_node,
                                             partial, maskpart, N);
    reduce_kernel<<<K, 256, 0, stream>>>(partial, maskpart, out_graph, NB);
}

// Round 2
// 231.228 us; speedup vs baseline: 1.2055x; 1.2055x over previous
//
#include <hip/hip_runtime.h>
#include <hip/hip_bf16.h>
#include <math.h>

#define EPSF 1e-5f

constexpr int D = 128;   // feature dim
constexpr int K = 128;   // centroids
constexpr int ROWS_PER_BLOCK = 64;   // 4 waves x 16 rows

typedef __bf16 bf16x8 __attribute__((ext_vector_type(8)));
typedef float  f32x4  __attribute__((ext_vector_type(4)));

// ---------------- kernel 1: centroid exp-map -> bf16 + c2 ----------------
__global__ __launch_bounds__(64) void prep_kernel(const float* __restrict__ w,
                                                  __bf16* __restrict__ crb,
                                                  float* __restrict__ c2) {
    int k = blockIdx.x;
    int t = threadIdx.x;
    float a = w[k * D + t];
    float b = w[k * D + t + 64];
    float ss = a * a + b * b;
#pragma unroll
    for (int off = 1; off < 64; off <<= 1)
        ss += __shfl_xor(ss, off, 64);
    float nrm   = sqrtf(ss);
    float nclip = fmaxf(nrm, EPSF);
    float targ  = fminf(nclip, 15.0f);
    float th    = tanhf(targ);
    float s     = th / nclip;
    crb[k * D + t]      = (__bf16)(a * s);
    crb[k * D + t + 64] = (__bf16)(b * s);
    if (t == 0) {
        float cn = s * nrm;
        c2[k] = cn * cn;
    }
}

// ---------------- kernel 2: MFMA pairwise distance ----------------
// 4 waves/block; wave w owns rows nbase+w*16 .. +15, all 128 cols.
// A-frag: x[rowbase + (lane&15)][ (lane>>4)*8 + j + 32*s ]  (cvt fp32->bf16)
// B-frag: crb[tk*16 + (lane&15)][ (lane>>4)*8 + j + 32*s ]  (direct bf16x8 load)
// C/D: col = lane&15 (within tile), row = (lane>>4)*4 + reg.
__global__ __launch_bounds__(256) void main_kernel(
        const float* __restrict__ x, const float* __restrict__ mask,
        const __bf16* __restrict__ crb, const float* __restrict__ c2g,
        float* __restrict__ out_node, float* __restrict__ partial,
        float* __restrict__ maskpart, int N) {
    __shared__ float sX2[ROWS_PER_BLOCK];
    __shared__ float sMask[ROWS_PER_BLOCK];
    __shared__ float sC2[K];
    __shared__ float sCol[4][K];

    const int t    = threadIdx.x;
    const int wave = t >> 6;
    const int lane = t & 63;
    const int m    = lane & 15;
    const int q    = lane >> 4;
    const int nbase   = blockIdx.x * ROWS_PER_BLOCK;
    const int rowbase = nbase + wave * 16;

    if (t < ROWS_PER_BLOCK) sMask[t] = mask[nbase + t];
    if (t < K) sC2[t] = c2g[t];

    const float*  xrow = x + (size_t)(rowbase + m) * D + q * 8;
    const __bf16* cb   = crb + (size_t)m * D + q * 8;

    f32x4 acc[8] = {};
    float ssq = 0.f;

#pragma unroll
    for (int s = 0; s < 4; s++) {
        float4 a0 = *(const float4*)(xrow + s * 32);
        float4 a1 = *(const float4*)(xrow + s * 32 + 4);
        ssq += a0.x*a0.x + a0.y*a0.y + a0.z*a0.z + a0.w*a0.w
             + a1.x*a1.x + a1.y*a1.y + a1.z*a1.z + a1.w*a1.w;
        bf16x8 av;
        av[0] = (__bf16)a0.x; av[1] = (__bf16)a0.y;
        av[2] = (__bf16)a0.z; av[3] = (__bf16)a0.w;
        av[4] = (__bf16)a1.x; av[5] = (__bf16)a1.y;
        av[6] = (__bf16)a1.z; av[7] = (__bf16)a1.w;
#pragma unroll
        for (int tk = 0; tk < 8; tk++) {
            bf16x8 bv = *(const bf16x8*)(cb + ((size_t)tk * 16) * D + s * 32);
            acc[tk] = __builtin_amdgcn_mfma_f32_16x16x32_bf16(av, bv, acc[tk], 0, 0, 0);
        }
    }

    // full-row sum of squares: rows live at lane&15 across the 4 quads
    ssq += __shfl_xor(ssq, 16, 64);
    ssq += __shfl_xor(ssq, 32, 64);
    if (lane < 16) sX2[wave * 16 + lane] = ssq;
    __syncthreads();

    // ---- epilogue ----
    float x2r[4], pxr[4], mvr[4];
#pragma unroll
    for (int i = 0; i < 4; i++) {
        int rl = wave * 16 + q * 4 + i;
        x2r[i] = sX2[rl];
        pxr[i] = 1.0f - x2r[i];
        mvr[i] = sMask[rl];
    }

    float colsum[8] = {0.f, 0.f, 0.f, 0.f, 0.f, 0.f, 0.f, 0.f};
#pragma unroll
    for (int tk = 0; tk < 8; tk++) {
        int col = tk * 16 + m;
        float c2v = sC2[col];
        float pc  = 1.0f - c2v;
#pragma unroll
        for (int i = 0; i < 4; i++) {
            int n = rowbase + q * 4 + i;
            float dot = acc[tk][i];
            float sq  = fmaxf(x2r[i] + c2v - 2.0f * dot, 0.0f);
            float den = fmaxf(pxr[i] * pc, EPSF);
            float arg = fmaf(2.0f * sq, __builtin_amdgcn_rcpf(den), 1.0f);
            arg = fmaxf(arg, 1.0f + 1e-7f);
            float dist = __logf(arg + __builtin_amdgcn_sqrtf(fmaf(arg, arg, -1.0f)));
            float val = dist * mvr[i];
            out_node[(size_t)n * K + col] = val;
            colsum[tk] += val;
        }
    }

    // column partial sums: reduce the 4 quads (same col, different rows)
#pragma unroll
    for (int tk = 0; tk < 8; tk++) {
        colsum[tk] += __shfl_xor(colsum[tk], 16, 64);
        colsum[tk] += __shfl_xor(colsum[tk], 32, 64);
    }
    if (lane < 16) {
#pragma unroll
        for (int tk = 0; tk < 8; tk++)
            sCol[wave][tk * 16 + lane] = colsum[tk];
    }
    __syncthreads();
    if (t < K)
        partial[(size_t)blockIdx.x * K + t] =
            sCol[0][t] + sCol[1][t] + sCol[2][t] + sCol[3][t];
    if (t == 0) {
        float msum = 0.f;
#pragma unroll
        for (int r = 0; r < ROWS_PER_BLOCK; r++) msum += sMask[r];
        maskpart[blockIdx.x] = msum;
    }
}

// ---------------- kernel 3: column reduce + divide by mask sum ----------------
__global__ __launch_bounds__(256) void reduce_kernel(
        const float* __restrict__ partial, const float* __restrict__ maskpart,
        float* __restrict__ out_graph, int NB) {
    int k = blockIdx.x;
    int t = threadIdx.x;
    float s = 0.f, mm = 0.f;
    for (int b = t; b < NB; b += 256) {
        s  += partial[(size_t)b * K + k];
        mm += maskpart[b];
    }
#pragma unroll
    for (int off = 1; off < 64; off <<= 1) {
        s  += __shfl_xor(s, off, 64);
        mm += __shfl_xor(mm, off, 64);
    }
    __shared__ float rs[4], rm[4];
    int w = t >> 6;
    if ((t & 63) == 0) { rs[w] = s; rm[w] = mm; }
    __syncthreads();
    if (t == 0) {
        float st = rs[0] + rs[1] + rs[2] + rs[3];
        float mt = rm[0] + rm[1] + rm[2] + rm[3];
        out_graph[k] = st / mt;
    }
}

extern "C" void kernel_launch(void* const* d_in, const int* in_sizes, int n_in,
                              void* d_out, int out_size, void* d_ws, size_t ws_size,
                              hipStream_t stream) {
    const float* node = (const float*)d_in[0];   // [N, D]
    const float* mask = (const float*)d_in[1];   // [N, 1]
    const float* w    = (const float*)d_in[2];   // [K, D]
    float* out = (float*)d_out;

    int N  = in_sizes[0] / D;                    // 200000
    int NB = N / ROWS_PER_BLOCK;                 // 3125 (exact)

    // ws layout: crb bf16[K*D] | c2[K] | partial[NB*K] | maskpart[NB]
    __bf16* crb     = (__bf16*)d_ws;
    float* c2       = (float*)(crb + K * D);
    float* partial  = c2 + K;
    float* maskpart = partial + (size_t)NB * K;

    float* out_graph = out;        // [K]
    float* out_node  = out + K;    // [N, K]

    prep_kernel<<<K, 64, 0, stream>>>(w, crb, c2);
    main_kernel<<<NB, 256, 0, stream>>>(node, mask, crb, c2, out_node,
                                        partial, maskpart, N);
    reduce_kernel<<<K, 256, 0, stream>>>(partial, maskpart, out_graph, NB);
}

// Round 3
// 196.504 us; speedup vs baseline: 1.4185x; 1.1767x over previous
//
#include <hip/hip_runtime.h>
#include <hip/hip_bf16.h>
#include <math.h>

#define EPSF 1e-5f

constexpr int D = 128;   // feature dim
constexpr int K = 128;   // centroids
constexpr int ROWS_PER_BLOCK = 64;   // 4 waves x 16 rows
constexpr int BPITCH = 272;          // LDS row pitch (bytes) for B tile: 4*m%32 start banks -> 2-way (free)

typedef __bf16 bf16x8 __attribute__((ext_vector_type(8)));
typedef float  f32x4  __attribute__((ext_vector_type(4)));

// ---------------- kernel 1: centroid exp-map -> bf16 + c2 ----------------
__global__ __launch_bounds__(64) void prep_kernel(const float* __restrict__ w,
                                                  __bf16* __restrict__ crb,
                                                  float* __restrict__ c2) {
    int k = blockIdx.x;
    int t = threadIdx.x;
    float a = w[k * D + t];
    float b = w[k * D + t + 64];
    float ss = a * a + b * b;
#pragma unroll
    for (int off = 1; off < 64; off <<= 1)
        ss += __shfl_xor(ss, off, 64);
    float nrm   = sqrtf(ss);
    float nclip = fmaxf(nrm, EPSF);
    float targ  = fminf(nclip, 15.0f);
    float th    = tanhf(targ);
    float s     = th / nclip;
    crb[k * D + t]      = (__bf16)(a * s);
    crb[k * D + t + 64] = (__bf16)(b * s);
    if (t == 0) {
        float cn = s * nrm;
        c2[k] = cn * cn;
    }
}

// ---------------- kernel 2: MFMA pairwise distance ----------------
// 4 waves/block, wave w owns rows rowbase..rowbase+15, all 128 cols.
// B tile staged in LDS (pitch 272 B). All global stores issued AFTER the
// final barrier so no s_barrier waits on vmcnt for them.
__global__ __launch_bounds__(256) void main_kernel(
        const float* __restrict__ x, const float* __restrict__ mask,
        const __bf16* __restrict__ crb, const float* __restrict__ c2g,
        float* __restrict__ out_node, float* __restrict__ partial,
        float* __restrict__ maskpart, int N) {
    __shared__ __align__(16) unsigned char sB[K * BPITCH];  // 34816 B
    __shared__ float sX2[ROWS_PER_BLOCK];
    __shared__ float sMask[ROWS_PER_BLOCK];
    __shared__ float sC2[K];
    __shared__ float sCol[4][K];

    const int t    = threadIdx.x;
    const int wave = t >> 6;
    const int lane = t & 63;
    const int m    = lane & 15;
    const int q    = lane >> 4;
    const int nbase   = blockIdx.x * ROWS_PER_BLOCK;
    const int rowbase = nbase + wave * 16;

    // ---- hoist all x loads (8 float4 = 128 B/lane) for max MLP ----
    const float* xrow = x + (size_t)(rowbase + m) * D + q * 8;
    float4 xr[8];
#pragma unroll
    for (int s = 0; s < 4; s++) {
        xr[2 * s]     = *(const float4*)(xrow + s * 32);
        xr[2 * s + 1] = *(const float4*)(xrow + s * 32 + 4);
    }

    // ---- stage B tile into LDS with pitch (coalesced global reads) ----
#pragma unroll
    for (int i = 0; i < 8; i++) {
        int f4  = t + 256 * i;        // 0..2047 float4s of crb
        int row = f4 >> 4;
        int c4  = f4 & 15;
        float4 v = ((const float4*)crb)[f4];
        *(float4*)(sB + row * BPITCH + c4 * 16) = v;
    }
    if (t < ROWS_PER_BLOCK) sMask[t] = mask[nbase + t];
    if (t < K) sC2[t] = c2g[t];

    // ---- row sum-sq + bf16 convert ----
    float ssq = 0.f;
    bf16x8 av[4];
#pragma unroll
    for (int s = 0; s < 4; s++) {
        float4 a0 = xr[2 * s], a1 = xr[2 * s + 1];
        ssq += a0.x*a0.x + a0.y*a0.y + a0.z*a0.z + a0.w*a0.w
             + a1.x*a1.x + a1.y*a1.y + a1.z*a1.z + a1.w*a1.w;
        av[s][0] = (__bf16)a0.x; av[s][1] = (__bf16)a0.y;
        av[s][2] = (__bf16)a0.z; av[s][3] = (__bf16)a0.w;
        av[s][4] = (__bf16)a1.x; av[s][5] = (__bf16)a1.y;
        av[s][6] = (__bf16)a1.z; av[s][7] = (__bf16)a1.w;
    }
    ssq += __shfl_xor(ssq, 16, 64);
    ssq += __shfl_xor(ssq, 32, 64);
    if (lane < 16) sX2[wave * 16 + lane] = ssq;

    __syncthreads();   // publishes sB, sX2, sMask, sC2

    // ---- MFMA loop: B-frags from LDS (ds_read_b128, 2-way = free) ----
    f32x4 acc[8] = {};
#pragma unroll
    for (int s = 0; s < 4; s++) {
#pragma unroll
        for (int tk = 0; tk < 8; tk++) {
            bf16x8 bv = *(const bf16x8*)(sB + (tk * 16 + m) * BPITCH + q * 16 + s * 64);
            acc[tk] = __builtin_amdgcn_mfma_f32_16x16x32_bf16(av[s], bv, acc[tk], 0, 0, 0);
        }
    }

    // ---- epilogue: distances into registers + column partials ----
    float x2r[4], pxr[4], mvr[4];
#pragma unroll
    for (int i = 0; i < 4; i++) {
        int rl = wave * 16 + q * 4 + i;
        x2r[i] = sX2[rl];
        pxr[i] = 1.0f - x2r[i];
        mvr[i] = sMask[rl];
    }

    float dv[8][4];
    float colsum[8];
#pragma unroll
    for (int tk = 0; tk < 8; tk++) {
        int col = tk * 16 + m;
        float c2v = sC2[col];
        float pc  = 1.0f - c2v;
        colsum[tk] = 0.f;
#pragma unroll
        for (int i = 0; i < 4; i++) {
            float dot = acc[tk][i];
            float sq  = fmaxf(x2r[i] + c2v - 2.0f * dot, 0.0f);
            float den = fmaxf(pxr[i] * pc, EPSF);
            float arg = fmaf(2.0f * sq, __builtin_amdgcn_rcpf(den), 1.0f);
            arg = fmaxf(arg, 1.0f + 1e-7f);
            float dist = __logf(arg + __builtin_amdgcn_sqrtf(fmaf(arg, arg, -1.0f)));
            float val = dist * mvr[i];
            dv[tk][i] = val;
            colsum[tk] += val;
        }
    }

    // column partial sums across the 4 quads (same col, different rows)
#pragma unroll
    for (int tk = 0; tk < 8; tk++) {
        colsum[tk] += __shfl_xor(colsum[tk], 16, 64);
        colsum[tk] += __shfl_xor(colsum[tk], 32, 64);
    }
    if (lane < 16) {
#pragma unroll
        for (int tk = 0; tk < 8; tk++)
            sCol[wave][tk * 16 + lane] = colsum[tk];
    }

    __syncthreads();   // only LDS writes pending -> cheap drain

    // ---- all global stores AFTER the last barrier (fire and forget) ----
    if (t < K)
        partial[(size_t)blockIdx.x * K + t] =
            sCol[0][t] + sCol[1][t] + sCol[2][t] + sCol[3][t];
    if (t == 0) {
        float msum = 0.f;
#pragma unroll
        for (int r = 0; r < ROWS_PER_BLOCK; r++) msum += sMask[r];
        maskpart[blockIdx.x] = msum;
    }
#pragma unroll
    for (int tk = 0; tk < 8; tk++) {
        int col = tk * 16 + m;
#pragma unroll
        for (int i = 0; i < 4; i++) {
            int n = rowbase + q * 4 + i;
            __builtin_nontemporal_store(dv[tk][i], &out_node[(size_t)n * K + col]);
        }
    }
}

// ---------------- kernel 3: column reduce + divide by mask sum ----------------
__global__ __launch_bounds__(256) void reduce_kernel(
        const float* __restrict__ partial, const float* __restrict__ maskpart,
        float* __restrict__ out_graph, int NB) {
    int k = blockIdx.x;
    int t = threadIdx.x;
    float s = 0.f, mm = 0.f;
    for (int b = t; b < NB; b += 256) {
        s  += partial[(size_t)b * K + k];
        mm += maskpart[b];
    }
#pragma unroll
    for (int off = 1; off < 64; off <<= 1) {
        s  += __shfl_xor(s, off, 64);
        mm += __shfl_xor(mm, off, 64);
    }
    __shared__ float rs[4], rm[4];
    int w = t >> 6;
    if ((t & 63) == 0) { rs[w] = s; rm[w] = mm; }
    __syncthreads();
    if (t == 0) {
        float st = rs[0] + rs[1] + rs[2] + rs[3];
        float mt = rm[0] + rm[1] + rm[2] + rm[3];
        out_graph[k] = st / mt;
    }
}

extern "C" void kernel_launch(void* const* d_in, const int* in_sizes, int n_in,
                              void* d_out, int out_size, void* d_ws, size_t ws_size,
                              hipStream_t stream) {
    const float* node = (const float*)d_in[0];   // [N, D]
    const float* mask = (const float*)d_in[1];   // [N, 1]
    const float* w    = (const float*)d_in[2];   // [K, D]
    float* out = (float*)d_out;

    int N  = in_sizes[0] / D;                    // 200000
    int NB = N / ROWS_PER_BLOCK;                 // 3125 (exact)

    // ws layout: crb bf16[K*D] | c2[K] | partial[NB*K] | maskpart[NB]
    __bf16* crb     = (__bf16*)d_ws;
    float* c2       = (float*)(crb + K * D);
    float* partial  = c2 + K;
    float* maskpart = partial + (size_t)NB * K;

    float* out_graph = out;        // [K]
    float* out_node  = out + K;    // [N, K]

    prep_kernel<<<K, 64, 0, stream>>>(w, crb, c2);
    main_kernel<<<NB, 256, 0, stream>>>(node, mask, crb, c2, out_node,
                                        partial, maskpart, N);
    reduce_kernel<<<K, 256, 0, stream>>>(partial, maskpart, out_graph, NB);
}